// Round 15
// baseline (194.011 us; speedup 1.0000x reference)
//
#include <hip/hip_runtime.h>
#include <hip/hip_bf16.h>
#include <math.h>

typedef __attribute__((ext_vector_type(8))) short short8;
typedef __attribute__((ext_vector_type(4))) float f32x4;

#define MFMA_BF16 __builtin_amdgcn_mfma_f32_16x16x32_bf16

static constexpr int Dm = 1024;
static constexpr int Tm = 2048;
static constexpr int Bb = 4;
static constexpr int NHm = 16;
static constexpr int HDm = 64;
static constexpr int Mtot = Bb * Tm;   // 8192
static constexpr int NKT = Tm / 64;    // 32 KV tiles per (b,h)
static constexpr int NTILE = Dm / 64;  // 16 K-tiles of 64
static constexpr float kQScale = 0.125f * 1.4426950408889634f;  // 1/sqrt(64) * log2(e)

__device__ __forceinline__ unsigned short f2bf(float f) {
  unsigned int u = __float_as_uint(f);
  u += 0x7FFFu + ((u >> 16) & 1u);  // RNE
  return (unsigned short)(u >> 16);
}

__device__ __forceinline__ float fexp2(float x) {  // raw v_exp_f32 (2^x)
  float r;
  asm("v_exp_f32 %0, %1" : "=v"(r) : "v"(x));
  return r;
}

__device__ __forceinline__ void gload16(const void* g, void* l) {
  __builtin_amdgcn_global_load_lds((const __attribute__((address_space(1))) void*)g,
                                   (__attribute__((address_space(3))) void*)l, 16, 0, 0);
}

// Fused conversion kernel (one launch): z<4 -> weight fp32->bf16 + transpose
// (Wt[n][k] = W[k][n]); z==4 -> X fp32->bf16 grid-stride convert.
__global__ __launch_bounds__(256) void cvt_all_kernel(
    const float* __restrict__ X, const float* __restrict__ W0,
    const float* __restrict__ W1, const float* __restrict__ W2,
    const float* __restrict__ W3, short* __restrict__ Xb,
    short* __restrict__ T0, short* __restrict__ T1,
    short* __restrict__ T2, short* __restrict__ T3) {
  const int tid = threadIdx.x;
  if (blockIdx.z == 4) {
    const int stride = 16 * 16 * 256;
    for (int i = (blockIdx.y * 16 + blockIdx.x) * 256 + tid; i < Mtot * Dm / 4;
         i += stride) {
      float4 v = reinterpret_cast<const float4*>(X)[i];
      short4 o;
      o.x = (short)f2bf(v.x);
      o.y = (short)f2bf(v.y);
      o.z = (short)f2bf(v.z);
      o.w = (short)f2bf(v.w);
      reinterpret_cast<short4*>(Xb)[i] = o;
    }
    return;
  }
  const float* W = blockIdx.z == 0 ? W0 : blockIdx.z == 1 ? W1 : blockIdx.z == 2 ? W2 : W3;
  short* Wt = blockIdx.z == 0 ? T0 : blockIdx.z == 1 ? T1 : blockIdx.z == 2 ? T2 : T3;
  __shared__ __align__(16) short T[64 * 72];
  const int k0 = blockIdx.y * 64, n0 = blockIdx.x * 64;
#pragma unroll
  for (int p = 0; p < 4; ++p) {
    int idx = tid + p * 256;
    int kr = idx >> 4, c4 = (idx & 15) * 4;
    float4 v = *reinterpret_cast<const float4*>(W + (size_t)(k0 + kr) * Dm + n0 + c4);
    T[(c4 + 0) * 72 + kr] = (short)f2bf(v.x);
    T[(c4 + 1) * 72 + kr] = (short)f2bf(v.y);
    T[(c4 + 2) * 72 + kr] = (short)f2bf(v.z);
    T[(c4 + 3) * 72 + kr] = (short)f2bf(v.w);
  }
  __syncthreads();
#pragma unroll
  for (int p = 0; p < 2; ++p) {
    int idx = tid + p * 256;
    int nr = idx >> 3, c8 = (idx & 7) * 8;
    *reinterpret_cast<short8*>(Wt + (size_t)(n0 + nr) * Dm + k0 + c8) =
        *reinterpret_cast<const short8*>(&T[nr * 72 + c8]);
  }
}

// ---------------- 256x256 8-phase GEMM — faithful template retry ------------
// r8 geometry (refcheck-passed) with the three template fixes: T5 setprio
// around MFMA, template phase order {reads; stage; barrier; lgkmcnt(0);
// MFMA; [vmcnt]; barrier}, no sched_barrier(0) walls (m141 failure mode).
// vmcnt(4) at p3/p7: buffer completion is needed 2 phases after its last
// half-tile stage; outstanding at checkpoint = next buffer's 2 half-tiles.

#define READA(CUR, MH)                                                        \
  {                                                                           \
    _Pragma("unroll") for (int mf = 0; mf < 4; ++mf) {                        \
      const int row_ = wr * 128 + (MH) * 64 + mf * 16 + lr;                   \
      _Pragma("unroll") for (int kk = 0; kk < 2; ++kk)                        \
          af[mf][kk] = *reinterpret_cast<const short8*>(                      \
              &AsL[CUR][row_ * 64 + (((kk * 4 + g) ^ (lr & 7)) << 3)]);       \
    }                                                                         \
  }

#define READB(CUR, NH)                                                        \
  {                                                                           \
    _Pragma("unroll") for (int nf = 0; nf < 2; ++nf) {                        \
      const int row_ = wc * 64 + (NH) * 32 + nf * 16 + lr;                    \
      _Pragma("unroll") for (int kk = 0; kk < 2; ++kk)                        \
          bf[nf][kk] = *reinterpret_cast<const short8*>(                      \
              &BsL[CUR][row_ * 64 + (((kk * 4 + g) ^ (lr & 7)) << 3)]);       \
    }                                                                         \
  }

#define QUAD(MH, NH)                                                          \
  {                                                                           \
    __builtin_amdgcn_s_setprio(1);                                            \
    _Pragma("unroll") for (int mf = 0; mf < 4; ++mf) {                        \
      _Pragma("unroll") for (int nf = 0; nf < 2; ++nf) {                      \
        acc[(MH) * 4 + mf][(NH) * 2 + nf] = MFMA_BF16(                        \
            af[mf][0], bf[nf][0], acc[(MH) * 4 + mf][(NH) * 2 + nf], 0, 0, 0);\
        acc[(MH) * 4 + mf][(NH) * 2 + nf] = MFMA_BF16(                        \
            af[mf][1], bf[nf][1], acc[(MH) * 4 + mf][(NH) * 2 + nf], 0, 0, 0);\
      }                                                                       \
    }                                                                         \
    __builtin_amdgcn_s_setprio(0);                                            \
  }

#define PH_OPEN                                                               \
  __builtin_amdgcn_s_barrier();                                               \
  asm volatile("s_waitcnt lgkmcnt(0)" ::: "memory");

#define PH_CLOSE __builtin_amdgcn_s_barrier();

#define PH_CLOSE_VM(COND)                                                     \
  if (COND) asm volatile("s_waitcnt vmcnt(4)" ::: "memory");                  \
  else      asm volatile("s_waitcnt vmcnt(0)" ::: "memory");                  \
  __builtin_amdgcn_s_barrier();

__global__ __launch_bounds__(512, 1) void gemm_qkv8_kernel(
    const short* __restrict__ Ags, const short* __restrict__ WT3,
    short* __restrict__ Qo, short* __restrict__ Ko, short* __restrict__ Vo) {
  __shared__ __align__(16) short AsL[2][256 * 64];
  __shared__ __align__(16) short BsL[2][256 * 64];
  const int tid = threadIdx.x;
  const int lane = tid & 63;
  const int w = tid >> 6;    // 0..7
  const int wr = w >> 2;     // 0..1 (M)
  const int wc = w & 3;      // 0..3 (N)
  const int g = lane >> 4;
  const int lr = lane & 15;
  const int m0 = blockIdx.x * 256;
  const int n0g = blockIdx.y * 256;
  const int sr8 = w * 8 + (lane >> 3);
  const int sch = ((lane & 7) ^ (lane >> 3)) << 3;

  auto stageH = [&](const short* G, int grow0, int kt, short* Ld) {
#pragma unroll
    for (int j = 0; j < 2; ++j)
      gload16(G + (size_t)(grow0 + j * 64 + sr8) * Dm + kt * 64 + sch,
              Ld + (j * 64 + w * 8) * 64);
  };

  f32x4 acc[8][4];
#pragma unroll
  for (int mi = 0; mi < 8; ++mi)
#pragma unroll
    for (int ni = 0; ni < 4; ++ni)
#pragma unroll
      for (int r = 0; r < 4; ++r) acc[mi][ni][r] = 0.f;

  short8 af[4][2], bf[2][2];

  // prologue: buf0 fully (tile0) + buf1.A0/B0 (tile1); wait buf0 complete
  stageH(Ags, m0, 0, &AsL[0][0]);
  stageH(WT3, n0g, 0, &BsL[0][0]);
  stageH(Ags, m0 + 128, 0, &AsL[0][128 * 64]);
  stageH(WT3, n0g + 128, 0, &BsL[0][128 * 64]);
  stageH(Ags, m0, 1, &AsL[1][0]);
  stageH(WT3, n0g, 1, &BsL[1][0]);
  asm volatile("s_waitcnt vmcnt(4)" ::: "memory");
  __builtin_amdgcn_s_barrier();

  for (int i = 0; i < NTILE / 2; ++i) {
    const int t0 = 2 * i, t1 = 2 * i + 1;
    const bool s0 = (t0 + 2 < NTILE), s1 = (t1 + 2 < NTILE);
    // p0: reads+stage -> quad(0,0) buf0 | stage buf1.A1 <- t1
    READA(0, 0); READB(0, 0);
    stageH(Ags, m0 + 128, t1, &AsL[1][128 * 64]);
    PH_OPEN; QUAD(0, 0); PH_CLOSE;
    // p1: quad(0,1) buf0 | stage buf1.B1 <- t1
    READB(0, 1);
    stageH(WT3, n0g + 128, t1, &BsL[1][128 * 64]);
    PH_OPEN; QUAD(0, 1); PH_CLOSE;
    // p2: quad(1,0) buf0 | stage buf0.A0 <- t0+2
    READA(0, 1); READB(0, 0);
    if (s0) stageH(Ags, m0, t0 + 2, &AsL[0][0]);
    PH_OPEN; QUAD(1, 0); PH_CLOSE;
    // p3: quad(1,1) buf0 | stage buf0.B0 <- t0+2 | vmcnt: buf1 ready for p4
    READB(0, 1);
    if (s0) stageH(WT3, n0g, t0 + 2, &BsL[0][0]);
    PH_OPEN; QUAD(1, 1); PH_CLOSE_VM(s0);
    // p4: quad(0,0) buf1 | stage buf0.A1 <- t0+2
    READA(1, 0); READB(1, 0);
    if (s0) stageH(Ags, m0 + 128, t0 + 2, &AsL[0][128 * 64]);
    PH_OPEN; QUAD(0, 0); PH_CLOSE;
    // p5: quad(0,1) buf1 | stage buf0.B1 <- t0+2
    READB(1, 1);
    if (s0) stageH(WT3, n0g + 128, t0 + 2, &BsL[0][128 * 64]);
    PH_OPEN; QUAD(0, 1); PH_CLOSE;
    // p6: quad(1,0) buf1 | stage buf1.A0 <- t1+2
    READA(1, 1); READB(1, 0);
    if (s1) stageH(Ags, m0, t1 + 2, &AsL[1][0]);
    PH_OPEN; QUAD(1, 0); PH_CLOSE;
    // p7: quad(1,1) buf1 | stage buf1.B0 <- t1+2 | vmcnt: buf0 ready for p0'
    READB(1, 1);
    if (s1) stageH(WT3, n0g, t1 + 2, &BsL[1][0]);
    PH_OPEN; QUAD(1, 1); PH_CLOSE_VM(s1);
  }

  // epilogue: z = weight selector, scatter per mode
  const int z = n0g >> 10;
  const int n0 = n0g & 1023;
  short* Co = z == 0 ? Qo : z == 1 ? Ko : Vo;
#pragma unroll
  for (int mi = 0; mi < 8; ++mi)
#pragma unroll
    for (int ni = 0; ni < 4; ++ni)
#pragma unroll
      for (int r = 0; r < 4; ++r) {
        int mg = m0 + wr * 128 + mi * 16 + g * 4 + r;  // C/D row=(lane>>4)*4+reg
        int ng = n0 + wc * 64 + ni * 16 + lr;          // C/D col=lane&15
        float v = acc[mi][ni][r];
        int b_ = mg >> 11, t_ = mg & 2047, h_ = ng >> 6, d_ = ng & 63;
        size_t bh = (size_t)(b_ * NHm + h_);
        if (z == 0) {
          Co[(bh * Tm + t_) * HDm + d_] = (short)f2bf(v * kQScale);
        } else if (z == 1) {
          Co[((bh * NKT + (t_ >> 6)) << 12) + (t_ & 63) * 64 + (d_ ^ ((t_ & 7) << 3))] =
              (short)f2bf(v);
        } else {
          Co[((bh * NKT + (t_ >> 6)) << 12) + d_ * 64 + ((t_ & 63) ^ ((d_ & 7) << 3))] =
              (short)f2bf(v);
        }
      }
}

// -------- Out-proj: CONTROL — r9/r13 128x128 BK=32 structure, unchanged -----
__device__ __forceinline__ void gemm_mainloop3(
    const short* __restrict__ A, const short* __restrict__ B,
    int m0, int n0, short* As, short* Bs, f32x4 acc[4][4], int tid) {
  const int lane = tid & 63;
  const int w = tid >> 6;
  const int wr = (w >> 1) * 64, wc = (w & 1) * 64;
  const int lr = lane & 15;
  const int g = lane >> 4;
  const int rowt = tid >> 2;
  const int csw = ((tid & 3) ^ ((tid >> 3) & 3)) * 8;

  const short* A0 = A + (size_t)(m0 + rowt) * Dm + csw;
  const short* A1 = A + (size_t)(m0 + 64 + rowt) * Dm + csw;
  const short* B0 = B + (size_t)(n0 + rowt) * Dm + csw;
  const short* B1 = B + (size_t)(n0 + 64 + rowt) * Dm + csw;
  short* Ad0 = As + (w * 16) * 32;
  short* Ad1 = As + (64 + w * 16) * 32;
  short* Bd0 = Bs + (w * 16) * 32;
  short* Bd1 = Bs + (64 + w * 16) * 32;

  auto stage = [&](int kt, int buf) {
    const int ko = kt * 32;
    gload16(A0 + ko, Ad0 + buf * 4096);
    gload16(A1 + ko, Ad1 + buf * 4096);
    gload16(B0 + ko, Bd0 + buf * 4096);
    gload16(B1 + ko, Bd1 + buf * 4096);
  };

  const int csel = (g ^ ((lr >> 1) & 3)) * 8;

  stage(0, 0);
  for (int kt = 0; kt < Dm / 32; ++kt) {
    __builtin_amdgcn_s_barrier();
    if (kt + 1 < Dm / 32) {
      stage(kt + 1, (kt + 1) & 1);
      __builtin_amdgcn_sched_barrier(0);
      asm volatile("s_waitcnt vmcnt(4)" ::: "memory");
    } else {
      asm volatile("s_waitcnt vmcnt(0)" ::: "memory");
    }
    __builtin_amdgcn_s_barrier();
    __builtin_amdgcn_sched_barrier(0);
    const int cur = kt & 1;
    short8 a[4], b[4];
#pragma unroll
    for (int mi = 0; mi < 4; ++mi)
      a[mi] = *reinterpret_cast<const short8*>(
          &As[cur * 4096 + (wr + mi * 16 + lr) * 32 + csel]);
#pragma unroll
    for (int ni = 0; ni < 4; ++ni)
      b[ni] = *reinterpret_cast<const short8*>(
          &Bs[cur * 4096 + (wc + ni * 16 + lr) * 32 + csel]);
#pragma unroll
    for (int mi = 0; mi < 4; ++mi)
#pragma unroll
      for (int ni = 0; ni < 4; ++ni)
        acc[mi][ni] = MFMA_BF16(a[mi], b[ni], acc[mi][ni], 0, 0, 0);
  }
}

__global__ __launch_bounds__(256) void gemm_out_kernel(
    const short* __restrict__ Ags, const short* __restrict__ Bts,
    float* __restrict__ Cf, const float* __restrict__ bias) {
  __shared__ __align__(16) short As[2 * 128 * 32];
  __shared__ __align__(16) short Bs[2 * 128 * 32];
  const int tid = threadIdx.x;
  const int m0 = blockIdx.x * 128;
  const int n0 = blockIdx.y * 128;

  f32x4 acc[4][4];
#pragma unroll
  for (int mi = 0; mi < 4; ++mi)
#pragma unroll
    for (int ni = 0; ni < 4; ++ni)
#pragma unroll
      for (int r = 0; r < 4; ++r) acc[mi][ni][r] = 0.f;

  gemm_mainloop3(Ags, Bts, m0, n0, As, Bs, acc, tid);

  const int lane = tid & 63;
  const int w = tid >> 6;
  const int wr = (w >> 1) * 64, wc = (w & 1) * 64;
  const int g = lane >> 4, lr = lane & 15;
#pragma unroll
  for (int mi = 0; mi < 4; ++mi)
#pragma unroll
    for (int ni = 0; ni < 4; ++ni)
#pragma unroll
      for (int r = 0; r < 4; ++r) {
        int mg = m0 + wr + mi * 16 + g * 4 + r;
        int ng = n0 + wc + ni * 16 + lr;
        Cf[(size_t)mg * Dm + ng] = acc[mi][ni][r] + bias[ng];
      }
}

// Flash attention (r13, unchanged): causal, fixed-offset softmax, l via
// ones-MFMA, 3-buffer 2-deep prefetch with counted vmcnt, XCD-local grid,
// T5 setprio on MFMA clusters.
__global__ __launch_bounds__(256) void attn_kernel(
    const short* __restrict__ Qg, const short* __restrict__ Kg,
    const short* __restrict__ Vg, short* __restrict__ Og) {
  __shared__ __align__(16) short Kl[3][64 * 64];
  __shared__ __align__(16) short Vl[3][64 * 64];
  __shared__ __align__(16) short Pl[4][32 * 72];
  const int tid = threadIdx.x;
  const int lane = tid & 63;
  const int w = tid >> 6;
  const int g = lane >> 4;
  const int lr = lane & 15;
  const int bh = blockIdx.x;
  const int pi = blockIdx.y;
  const short* Ks = Kg + ((size_t)bh * NKT << 12);
  const short* Vs = Vg + ((size_t)bh * NKT << 12);
  short* Pw = &Pl[w][0];
  const int b_ = bh >> 4, h_ = bh & 15;

  short8 ones;
#pragma unroll
  for (int j = 0; j < 8; ++j) ones[j] = (short)0x3F80;  // bf16 1.0

  auto stage = [&](int t, int buf) {
#pragma unroll
    for (int i = 0; i < 2; ++i) {
      int ch = w * 2 + i;
      gload16(Ks + ((size_t)t << 12) + ch * 512 + lane * 8, &Kl[buf][ch * 512]);
      gload16(Vs + ((size_t)t << 12) + ch * 512 + lane * 8, &Vl[buf][ch * 512]);
    }
  };

  for (int pass = 0; pass < 2; ++pass) {
    const int qb = pass == 0 ? (15 - pi) : pi;
    const int q0 = qb * 128;
    const int qw = q0 + w * 32;
    const short* Qs = Qg + ((size_t)bh * Tm + q0) * HDm;

    short8 qf[2][2];
#pragma unroll
    for (int mi = 0; mi < 2; ++mi)
#pragma unroll
      for (int kk = 0; kk < 2; ++kk)
        qf[mi][kk] = *reinterpret_cast<const short8*>(
            Qs + (w * 32 + mi * 16 + lr) * HDm + kk * 32 + g * 8);

    f32x4 o[2][4], lacc[2];
#pragma unroll
    for (int mi = 0; mi < 2; ++mi)
#pragma unroll
      for (int r = 0; r < 4; ++r) {
        lacc[mi][r] = 0.f;
#pragma unroll
        for (int di = 0; di < 4; ++di) o[mi][di][r] = 0.f;
      }

    const int nt = q0 / 64 + 2;
    stage(0, 0);
    stage(1, 1);
    for (int t = 0; t < nt; ++t) {
      if (t < nt - 1) asm volatile("s_waitcnt vmcnt(4)" ::: "memory");
      else            asm volatile("s_waitcnt vmcnt(0)" ::: "memory");
      __builtin_amdgcn_s_barrier();
      __builtin_amdgcn_sched_barrier(0);
      if (t + 2 < nt) stage(t + 2, (t + 2) % 3);
      const int cur = t % 3;
      const int k0 = t * 64;
      const bool active = (k0 <= qw + 31);
      if (active) {
        short8 kf[2][4];
#pragma unroll
        for (int ni = 0; ni < 4; ++ni) {
          int row = ni * 16 + lr;
#pragma unroll
          for (int kk = 0; kk < 2; ++kk)
            kf[kk][ni] = *reinterpret_cast<const short8*>(
                &Kl[cur][row * 64 + ((kk * 32 + g * 8) ^ ((row & 7) << 3))]);
        }
        f32x4 s[2][4];
        __builtin_amdgcn_s_setprio(1);
#pragma unroll
        for (int mi = 0; mi < 2; ++mi)
#pragma unroll
          for (int ni = 0; ni < 4; ++ni) {
            f32x4 acc;
#pragma unroll
            for (int r = 0; r < 4; ++r) acc[r] = 0.f;
            acc = MFMA_BF16(qf[mi][0], kf[0][ni], acc, 0, 0, 0);
            acc = MFMA_BF16(qf[mi][1], kf[1][ni], acc, 0, 0, 0);
            s[mi][ni] = acc;
          }
        __builtin_amdgcn_s_setprio(0);
        if (k0 + 63 > qw) {
#pragma unroll
          for (int mi = 0; mi < 2; ++mi)
#pragma unroll
            for (int ni = 0; ni < 4; ++ni)
#pragma unroll
              for (int r = 0; r < 4; ++r)
                if (k0 + ni * 16 + lr > qw + mi * 16 + g * 4 + r) s[mi][ni][r] = -1e30f;
        }
#pragma unroll
        for (int mi = 0; mi < 2; ++mi)
#pragma unroll
          for (int ni = 0; ni < 4; ++ni)
#pragma unroll
            for (int r = 0; r < 4; ++r)
              Pw[(mi * 16 + g * 4 + r) * 72 + ((ni * 16 + lr) ^ (g << 4))] =
                  (short)f2bf(fexp2(s[mi][ni][r]));

        __builtin_amdgcn_s_setprio(1);
#pragma unroll
        for (int kk = 0; kk < 2; ++kk) {
          short8 pf[2];
#pragma unroll
          for (int mi = 0; mi < 2; ++mi)
            pf[mi] = *reinterpret_cast<const short8*>(
                &Pw[(mi * 16 + lr) * 72 + ((kk * 32 + g * 8) ^ ((lr >> 2) << 4))]);
#pragma unroll
          for (int mi = 0; mi < 2; ++mi)
            lacc[mi] = MFMA_BF16(pf[mi], ones, lacc[mi], 0, 0, 0);
#pragma unroll
          for (int di = 0; di < 4; ++di) {
            int d = di * 16 + lr;
            short8 vf = *reinterpret_cast<const short8*>(
                &Vl[cur][d * 64 + ((kk * 32 + g * 8) ^ ((d & 7) << 3))]);
#pragma unroll
            for (int mi = 0; mi < 2; ++mi)
              o[mi][di] = MFMA_BF16(pf[mi], vf, o[mi][di], 0, 0, 0);
          }
        }
        __builtin_amdgcn_s_setprio(0);
      }
    }
    __syncthreads();

#pragma unroll
    for (int mi = 0; mi < 2; ++mi)
#pragma unroll
      for (int di = 0; di < 4; ++di)
#pragma unroll
        for (int r = 0; r < 4; ++r) {
          float ov = o[mi][di][r] / lacc[mi][r];
          int qg = q0 + w * 32 + mi * 16 + g * 4 + r;
          int d_ = di * 16 + lr;
          Og[((size_t)b_ * Tm + qg) * Dm + h_ * HDm + d_] = (short)f2bf(ov);
        }
  }
}

extern "C" void kernel_launch(void* const* d_in, const int* in_sizes, int n_in,
                              void* d_out, int out_size, void* d_ws, size_t ws_size,
                              hipStream_t stream) {
  const float* X = (const float*)d_in[0];
  const float* Wq = (const float*)d_in[1];
  const float* Wk = (const float*)d_in[2];
  const float* Wv = (const float*)d_in[3];
  const float* Wo = (const float*)d_in[4];
  const float* bo = (const float*)d_in[5];
  float* out = (float*)d_out;

  char* ws = (char*)d_ws;
  short* Xb = (short*)ws;  ws += (size_t)Mtot * Dm * 2;
  short* Wqt = (short*)ws; ws += (size_t)Dm * Dm * 2;  // [3072][1024] contiguous
  short* Wkt = (short*)ws; ws += (size_t)Dm * Dm * 2;
  short* Wvt = (short*)ws; ws += (size_t)Dm * Dm * 2;
  short* Wot = (short*)ws; ws += (size_t)Dm * Dm * 2;
  short* Qb = (short*)ws;  ws += (size_t)Mtot * Dm * 2;
  short* Kb = (short*)ws;  ws += (size_t)Mtot * Dm * 2;
  short* Vb = (short*)ws;  ws += (size_t)Mtot * Dm * 2;
  short* Ab = (short*)ws;  ws += (size_t)Mtot * Dm * 2;

  cvt_all_kernel<<<dim3(16, 16, 5), 256, 0, stream>>>(
      X, Wq, Wk, Wv, Wo, Xb, Wqt, Wkt, Wvt, Wot);

  gemm_qkv8_kernel<<<dim3(Mtot / 256, 3 * Dm / 256), 512, 0, stream>>>(
      Xb, Wqt, Qb, Kb, Vb);

  attn_kernel<<<dim3(Bb * NHm, 8), 256, 0, stream>>>(Qb, Kb, Vb, Ab);

  gemm_out_kernel<<<dim3(Mtot / 128, Dm / 128), 256, 0, stream>>>(Ab, Wot, out, bo);
}

// Round 16
// 188.598 us; speedup vs baseline: 1.0287x; 1.0287x over previous
//
#include <hip/hip_runtime.h>
#include <hip/hip_bf16.h>
#include <math.h>

typedef __attribute__((ext_vector_type(8))) short short8;
typedef __attribute__((ext_vector_type(4))) float f32x4;

#define MFMA_BF16 __builtin_amdgcn_mfma_f32_16x16x32_bf16

static constexpr int Dm = 1024;
static constexpr int Tm = 2048;
static constexpr int Bb = 4;
static constexpr int NHm = 16;
static constexpr int HDm = 64;
static constexpr int Mtot = Bb * Tm;   // 8192
static constexpr int NKT = Tm / 64;    // 32 KV tiles per (b,h)
static constexpr float kQScale = 0.125f * 1.4426950408889634f;  // 1/sqrt(64) * log2(e)

__device__ __forceinline__ unsigned short f2bf(float f) {
  unsigned int u = __float_as_uint(f);
  u += 0x7FFFu + ((u >> 16) & 1u);  // RNE
  return (unsigned short)(u >> 16);
}

__device__ __forceinline__ float fexp2(float x) {  // raw v_exp_f32 (2^x)
  float r;
  asm("v_exp_f32 %0, %1" : "=v"(r) : "v"(x));
  return r;
}

__device__ __forceinline__ void gload16(const void* g, void* l) {
  __builtin_amdgcn_global_load_lds((const __attribute__((address_space(1))) void*)g,
                                   (__attribute__((address_space(3))) void*)l, 16, 0, 0);
}

// Fused conversion kernel (one launch): z<4 -> weight fp32->bf16 + transpose
// (Wt[n][k] = W[k][n]); z==4 -> X fp32->bf16 grid-stride convert.
__global__ __launch_bounds__(256) void cvt_all_kernel(
    const float* __restrict__ X, const float* __restrict__ W0,
    const float* __restrict__ W1, const float* __restrict__ W2,
    const float* __restrict__ W3, short* __restrict__ Xb,
    short* __restrict__ T0, short* __restrict__ T1,
    short* __restrict__ T2, short* __restrict__ T3) {
  const int tid = threadIdx.x;
  if (blockIdx.z == 4) {
    const int stride = 16 * 16 * 256;
    for (int i = (blockIdx.y * 16 + blockIdx.x) * 256 + tid; i < Mtot * Dm / 4;
         i += stride) {
      float4 v = reinterpret_cast<const float4*>(X)[i];
      short4 o;
      o.x = (short)f2bf(v.x);
      o.y = (short)f2bf(v.y);
      o.z = (short)f2bf(v.z);
      o.w = (short)f2bf(v.w);
      reinterpret_cast<short4*>(Xb)[i] = o;
    }
    return;
  }
  const float* W = blockIdx.z == 0 ? W0 : blockIdx.z == 1 ? W1 : blockIdx.z == 2 ? W2 : W3;
  short* Wt = blockIdx.z == 0 ? T0 : blockIdx.z == 1 ? T1 : blockIdx.z == 2 ? T2 : T3;
  __shared__ __align__(16) short T[64 * 72];
  const int k0 = blockIdx.y * 64, n0 = blockIdx.x * 64;
#pragma unroll
  for (int p = 0; p < 4; ++p) {
    int idx = tid + p * 256;
    int kr = idx >> 4, c4 = (idx & 15) * 4;
    float4 v = *reinterpret_cast<const float4*>(W + (size_t)(k0 + kr) * Dm + n0 + c4);
    T[(c4 + 0) * 72 + kr] = (short)f2bf(v.x);
    T[(c4 + 1) * 72 + kr] = (short)f2bf(v.y);
    T[(c4 + 2) * 72 + kr] = (short)f2bf(v.z);
    T[(c4 + 3) * 72 + kr] = (short)f2bf(v.w);
  }
  __syncthreads();
#pragma unroll
  for (int p = 0; p < 2; ++p) {
    int idx = tid + p * 256;
    int nr = idx >> 3, c8 = (idx & 7) * 8;
    *reinterpret_cast<short8*>(Wt + (size_t)(n0 + nr) * Dm + k0 + c8) =
        *reinterpret_cast<const short8*>(&T[nr * 72 + c8]);
  }
}

// Hybrid 2-phase 128x128/BK=32 mainloop (best-measured, r9/r13): 2 LDS
// buffers (32 KB) + counted vmcnt so the barrier never drains the fresh
// prefetch. At the wait: outstanding = 4 (tile kt) + 4 (tile kt+1) ->
// vmcnt(4) retires exactly tile kt. Last iteration drains.
// LDS chunk-swizzle (verified 0 conflicts): LDS(r,c16) holds global chunk
// c16 ^ ((r>>1)&3), applied on the global SOURCE address (rule #21);
// fragment reads use chunk (g ^ ((lr>>1)&3)) -> 2 lanes/bank = free.
__device__ __forceinline__ void gemm_mainloop3(
    const short* __restrict__ A, const short* __restrict__ B,
    int m0, int n0, short* As, short* Bs, f32x4 acc[4][4], int tid) {
  const int lane = tid & 63;
  const int w = tid >> 6;
  const int wr = (w >> 1) * 64, wc = (w & 1) * 64;
  const int lr = lane & 15;
  const int g = lane >> 4;
  const int rowt = tid >> 2;
  const int csw = ((tid & 3) ^ ((tid >> 3) & 3)) * 8;

  const short* A0 = A + (size_t)(m0 + rowt) * Dm + csw;
  const short* A1 = A + (size_t)(m0 + 64 + rowt) * Dm + csw;
  const short* B0 = B + (size_t)(n0 + rowt) * Dm + csw;
  const short* B1 = B + (size_t)(n0 + 64 + rowt) * Dm + csw;
  short* Ad0 = As + (w * 16) * 32;
  short* Ad1 = As + (64 + w * 16) * 32;
  short* Bd0 = Bs + (w * 16) * 32;
  short* Bd1 = Bs + (64 + w * 16) * 32;

  auto stage = [&](int kt, int buf) {
    const int ko = kt * 32;
    gload16(A0 + ko, Ad0 + buf * 4096);
    gload16(A1 + ko, Ad1 + buf * 4096);
    gload16(B0 + ko, Bd0 + buf * 4096);
    gload16(B1 + ko, Bd1 + buf * 4096);
  };

  const int csel = (g ^ ((lr >> 1) & 3)) * 8;

  stage(0, 0);
  for (int kt = 0; kt < Dm / 32; ++kt) {
    __builtin_amdgcn_s_barrier();  // prior iteration's readers of dst buf done
    if (kt + 1 < Dm / 32) {
      stage(kt + 1, (kt + 1) & 1);
      __builtin_amdgcn_sched_barrier(0);
      asm volatile("s_waitcnt vmcnt(4)" ::: "memory");  // tile-kt loads only
    } else {
      asm volatile("s_waitcnt vmcnt(0)" ::: "memory");
    }
    __builtin_amdgcn_s_barrier();  // publish tile-kt LDS to all waves
    __builtin_amdgcn_sched_barrier(0);
    const int cur = kt & 1;
    short8 a[4], b[4];
#pragma unroll
    for (int mi = 0; mi < 4; ++mi)
      a[mi] = *reinterpret_cast<const short8*>(
          &As[cur * 4096 + (wr + mi * 16 + lr) * 32 + csel]);
#pragma unroll
    for (int ni = 0; ni < 4; ++ni)
      b[ni] = *reinterpret_cast<const short8*>(
          &Bs[cur * 4096 + (wc + ni * 16 + lr) * 32 + csel]);
#pragma unroll
    for (int mi = 0; mi < 4; ++mi)
#pragma unroll
      for (int ni = 0; ni < 4; ++ni)
        acc[mi][ni] = MFMA_BF16(a[mi], b[ni], acc[mi][ni], 0, 0, 0);
  }
}

// Fused QKV as ONE GEMM: A(8192x1024) @ WT3^T, WT3 = [Wq;Wk;Wv]^T [3072][1024].
// grid = (m=64, n=24): same-m blocks have id%8 == m%8 -> same XCD L2.
__global__ __launch_bounds__(256) void gemm_qkv_kernel(
    const short* __restrict__ Ags, const short* __restrict__ WT3,
    short* __restrict__ Qo, short* __restrict__ Ko, short* __restrict__ Vo) {
  __shared__ __align__(16) short As[2 * 128 * 32];
  __shared__ __align__(16) short Bs[2 * 128 * 32];
  const int tid = threadIdx.x;
  const int m0 = blockIdx.x * 128;
  const int n0g = blockIdx.y * 128;  // 0..3071
  const int z = n0g >> 10;
  const int n0 = n0g & 1023;
  short* Co = z == 0 ? Qo : z == 1 ? Ko : Vo;

  f32x4 acc[4][4];
#pragma unroll
  for (int mi = 0; mi < 4; ++mi)
#pragma unroll
    for (int ni = 0; ni < 4; ++ni)
#pragma unroll
      for (int r = 0; r < 4; ++r) acc[mi][ni][r] = 0.f;

  gemm_mainloop3(Ags, WT3, m0, n0g, As, Bs, acc, tid);

  const int lane = tid & 63;
  const int w = tid >> 6;
  const int wr = (w >> 1) * 64, wc = (w & 1) * 64;
  const int g = lane >> 4, lr = lane & 15;
#pragma unroll
  for (int mi = 0; mi < 4; ++mi)
#pragma unroll
    for (int ni = 0; ni < 4; ++ni)
#pragma unroll
      for (int r = 0; r < 4; ++r) {
        int mg = m0 + wr + mi * 16 + g * 4 + r;  // C/D: row=(lane>>4)*4+reg
        int ng = n0 + wc + ni * 16 + lr;         // C/D: col=lane&15
        float v = acc[mi][ni][r];
        int b_ = mg >> 11, t_ = mg & 2047, h_ = ng >> 6, d_ = ng & 63;
        size_t bh = (size_t)(b_ * NHm + h_);
        if (z == 0) {
          Co[(bh * Tm + t_) * HDm + d_] = (short)f2bf(v * kQScale);
        } else if (z == 1) {
          Co[((bh * NKT + (t_ >> 6)) << 12) + (t_ & 63) * 64 + (d_ ^ ((t_ & 7) << 3))] =
              (short)f2bf(v);
        } else {
          Co[((bh * NKT + (t_ >> 6)) << 12) + d_ * 64 + ((t_ & 63) ^ ((d_ & 7) << 3))] =
              (short)f2bf(v);
        }
      }
}

// Out-projection: fp32 + bias, row-major. grid = (m=64, n=8) = 512 blocks.
__global__ __launch_bounds__(256) void gemm_out_kernel(
    const short* __restrict__ Ags, const short* __restrict__ Bts,
    float* __restrict__ Cf, const float* __restrict__ bias) {
  __shared__ __align__(16) short As[2 * 128 * 32];
  __shared__ __align__(16) short Bs[2 * 128 * 32];
  const int tid = threadIdx.x;
  const int m0 = blockIdx.x * 128;
  const int n0 = blockIdx.y * 128;

  f32x4 acc[4][4];
#pragma unroll
  for (int mi = 0; mi < 4; ++mi)
#pragma unroll
    for (int ni = 0; ni < 4; ++ni)
#pragma unroll
      for (int r = 0; r < 4; ++r) acc[mi][ni][r] = 0.f;

  gemm_mainloop3(Ags, Bts, m0, n0, As, Bs, acc, tid);

  const int lane = tid & 63;
  const int w = tid >> 6;
  const int wr = (w >> 1) * 64, wc = (w & 1) * 64;
  const int g = lane >> 4, lr = lane & 15;
#pragma unroll
  for (int mi = 0; mi < 4; ++mi)
#pragma unroll
    for (int ni = 0; ni < 4; ++ni)
#pragma unroll
      for (int r = 0; r < 4; ++r) {
        int mg = m0 + wr + mi * 16 + g * 4 + r;
        int ng = n0 + wc + ni * 16 + lr;
        Cf[(size_t)mg * Dm + ng] = acc[mi][ni][r] + bias[ng];
      }
}

// Flash attention (r13, best-measured): causal, fixed-offset softmax (scores
// bounded; exp2 safe in f32; scale cancels in O=PV/l), l via ones-MFMA,
// 3-buffer 2-deep prefetch with counted vmcnt, XCD-local grid, T5 setprio.
__global__ __launch_bounds__(256) void attn_kernel(
    const short* __restrict__ Qg, const short* __restrict__ Kg,
    const short* __restrict__ Vg, short* __restrict__ Og) {
  __shared__ __align__(16) short Kl[3][64 * 64];
  __shared__ __align__(16) short Vl[3][64 * 64];
  __shared__ __align__(16) short Pl[4][32 * 72];
  const int tid = threadIdx.x;
  const int lane = tid & 63;
  const int w = tid >> 6;
  const int g = lane >> 4;
  const int lr = lane & 15;
  const int bh = blockIdx.x;
  const int pi = blockIdx.y;
  const short* Ks = Kg + ((size_t)bh * NKT << 12);
  const short* Vs = Vg + ((size_t)bh * NKT << 12);
  short* Pw = &Pl[w][0];
  const int b_ = bh >> 4, h_ = bh & 15;

  short8 ones;
#pragma unroll
  for (int j = 0; j < 8; ++j) ones[j] = (short)0x3F80;  // bf16 1.0

  auto stage = [&](int t, int buf) {
#pragma unroll
    for (int i = 0; i < 2; ++i) {
      int ch = w * 2 + i;
      gload16(Ks + ((size_t)t << 12) + ch * 512 + lane * 8, &Kl[buf][ch * 512]);
      gload16(Vs + ((size_t)t << 12) + ch * 512 + lane * 8, &Vl[buf][ch * 512]);
    }
  };

  for (int pass = 0; pass < 2; ++pass) {
    const int qb = pass == 0 ? (15 - pi) : pi;
    const int q0 = qb * 128;
    const int qw = q0 + w * 32;
    const short* Qs = Qg + ((size_t)bh * Tm + q0) * HDm;

    short8 qf[2][2];
#pragma unroll
    for (int mi = 0; mi < 2; ++mi)
#pragma unroll
      for (int kk = 0; kk < 2; ++kk)
        qf[mi][kk] = *reinterpret_cast<const short8*>(
            Qs + (w * 32 + mi * 16 + lr) * HDm + kk * 32 + g * 8);

    f32x4 o[2][4], lacc[2];
#pragma unroll
    for (int mi = 0; mi < 2; ++mi)
#pragma unroll
      for (int r = 0; r < 4; ++r) {
        lacc[mi][r] = 0.f;
#pragma unroll
        for (int di = 0; di < 4; ++di) o[mi][di][r] = 0.f;
      }

    const int nt = q0 / 64 + 2;
    stage(0, 0);
    stage(1, 1);
    for (int t = 0; t < nt; ++t) {
      if (t < nt - 1) asm volatile("s_waitcnt vmcnt(4)" ::: "memory");
      else            asm volatile("s_waitcnt vmcnt(0)" ::: "memory");
      __builtin_amdgcn_s_barrier();
      __builtin_amdgcn_sched_barrier(0);
      if (t + 2 < nt) stage(t + 2, (t + 2) % 3);
      const int cur = t % 3;
      const int k0 = t * 64;
      const bool active = (k0 <= qw + 31);
      if (active) {
        short8 kf[2][4];
#pragma unroll
        for (int ni = 0; ni < 4; ++ni) {
          int row = ni * 16 + lr;
#pragma unroll
          for (int kk = 0; kk < 2; ++kk)
            kf[kk][ni] = *reinterpret_cast<const short8*>(
                &Kl[cur][row * 64 + ((kk * 32 + g * 8) ^ ((row & 7) << 3))]);
        }
        f32x4 s[2][4];
        __builtin_amdgcn_s_setprio(1);
#pragma unroll
        for (int mi = 0; mi < 2; ++mi)
#pragma unroll
          for (int ni = 0; ni < 4; ++ni) {
            f32x4 acc;
#pragma unroll
            for (int r = 0; r < 4; ++r) acc[r] = 0.f;
            acc = MFMA_BF16(qf[mi][0], kf[0][ni], acc, 0, 0, 0);
            acc = MFMA_BF16(qf[mi][1], kf[1][ni], acc, 0, 0, 0);
            s[mi][ni] = acc;
          }
        __builtin_amdgcn_s_setprio(0);
        if (k0 + 63 > qw) {
#pragma unroll
          for (int mi = 0; mi < 2; ++mi)
#pragma unroll
            for (int ni = 0; ni < 4; ++ni)
#pragma unroll
              for (int r = 0; r < 4; ++r)
                if (k0 + ni * 16 + lr > qw + mi * 16 + g * 4 + r) s[mi][ni][r] = -1e30f;
        }
#pragma unroll
        for (int mi = 0; mi < 2; ++mi)
#pragma unroll
          for (int ni = 0; ni < 4; ++ni)
#pragma unroll
            for (int r = 0; r < 4; ++r)
              Pw[(mi * 16 + g * 4 + r) * 72 + ((ni * 16 + lr) ^ (g << 4))] =
                  (short)f2bf(fexp2(s[mi][ni][r]));

        __builtin_amdgcn_s_setprio(1);
#pragma unroll
        for (int kk = 0; kk < 2; ++kk) {
          short8 pf[2];
#pragma unroll
          for (int mi = 0; mi < 2; ++mi)
            pf[mi] = *reinterpret_cast<const short8*>(
                &Pw[(mi * 16 + lr) * 72 + ((kk * 32 + g * 8) ^ ((lr >> 2) << 4))]);
#pragma unroll
          for (int mi = 0; mi < 2; ++mi)
            lacc[mi] = MFMA_BF16(pf[mi], ones, lacc[mi], 0, 0, 0);
#pragma unroll
          for (int di = 0; di < 4; ++di) {
            int d = di * 16 + lr;
            short8 vf = *reinterpret_cast<const short8*>(
                &Vl[cur][d * 64 + ((kk * 32 + g * 8) ^ ((d & 7) << 3))]);
#pragma unroll
            for (int mi = 0; mi < 2; ++mi)
              o[mi][di] = MFMA_BF16(pf[mi], vf, o[mi][di], 0, 0, 0);
          }
        }
        __builtin_amdgcn_s_setprio(0);
      }
    }
    __syncthreads();

#pragma unroll
    for (int mi = 0; mi < 2; ++mi)
#pragma unroll
      for (int di = 0; di < 4; ++di)
#pragma unroll
        for (int r = 0; r < 4; ++r) {
          float ov = o[mi][di][r] / lacc[mi][r];
          int qg = q0 + w * 32 + mi * 16 + g * 4 + r;
          int d_ = di * 16 + lr;
          Og[((size_t)b_ * Tm + qg) * Dm + h_ * HDm + d_] = (short)f2bf(ov);
        }
  }
}

extern "C" void kernel_launch(void* const* d_in, const int* in_sizes, int n_in,
                              void* d_out, int out_size, void* d_ws, size_t ws_size,
                              hipStream_t stream) {
  const float* X = (const float*)d_in[0];
  const float* Wq = (const float*)d_in[1];
  const float* Wk = (const float*)d_in[2];
  const float* Wv = (const float*)d_in[3];
  const float* Wo = (const float*)d_in[4];
  const float* bo = (const float*)d_in[5];
  float* out = (float*)d_out;

  char* ws = (char*)d_ws;
  short* Xb = (short*)ws;  ws += (size_t)Mtot * Dm * 2;
  short* Wqt = (short*)ws; ws += (size_t)Dm * Dm * 2;  // [3072][1024] contiguous
  short* Wkt = (short*)ws; ws += (size_t)Dm * Dm * 2;
  short* Wvt = (short*)ws; ws += (size_t)Dm * Dm * 2;
  short* Wot = (short*)ws; ws += (size_t)Dm * Dm * 2;
  short* Qb = (short*)ws;  ws += (size_t)Mtot * Dm * 2;
  short* Kb = (short*)ws;  ws += (size_t)Mtot * Dm * 2;
  short* Vb = (short*)ws;  ws += (size_t)Mtot * Dm * 2;
  short* Ab = (short*)ws;  ws += (size_t)Mtot * Dm * 2;

  cvt_all_kernel<<<dim3(16, 16, 5), 256, 0, stream>>>(
      X, Wq, Wk, Wv, Wo, Xb, Wqt, Wkt, Wvt, Wot);

  gemm_qkv_kernel<<<dim3(Mtot / 128, 3 * Dm / 128), 256, 0, stream>>>(
      Xb, Wqt, Qb, Kb, Vb);

  attn_kernel<<<dim3(Bb * NHm, 8), 256, 0, stream>>>(Qb, Kb, Vb, Ab);

  gemm_out_kernel<<<dim3(Mtot / 128, Dm / 128), 256, 0, stream>>>(Ab, Wot, out, bo);
}